// Round 1
// baseline (260.061 us; speedup 1.0000x reference)
//
#include <hip/hip_runtime.h>

#define B_SZ    16
#define T_LEN   1024
#define C_CH    32
#define TC      (T_LEN * C_CH)      // 32768
#define S_MAIN  128
#define NB_P    400
#define P_TOP   60
#define KDIM    128
#define STRETCH 8
#define OUT_CH  (NB_P + P_TOP)      // 460

// ---------------------------------------------------------------------------
// Kernel 1: transpose x [B, T*C] -> xT [T*C, B] so a gather of one index
// reads 16 consecutive floats (one 64B line) covering all batches.
// ---------------------------------------------------------------------------
__global__ __launch_bounds__(256) void transpose_x(const float* __restrict__ x,
                                                   float* __restrict__ xT) {
    __shared__ float tile[16][129];   // +1 pad breaks 16-way bank conflict
    const int i0 = blockIdx.x * 128;
    const int t  = threadIdx.x;       // 0..255
    #pragma unroll
    for (int r = 0; r < 8; ++r) {
        int e  = r * 256 + t;
        int b  = e >> 7;              // /128
        int ii = e & 127;
        tile[b][ii] = x[b * TC + i0 + ii];
    }
    __syncthreads();
    #pragma unroll
    for (int r = 0; r < 8; ++r) {
        int e  = r * 256 + t;
        int ii = e >> 4;              // /16
        int b  = e & 15;
        xT[i0 * 16 + e] = tile[b][ii];   // (i0+ii)*16 + b == i0*16 + e
    }
}

// ---------------------------------------------------------------------------
// Patch compute: one wave per (row, patch) pair.
// lane = j*4 + bq :  j in [0,16) = k-chunk of 8, bq in [0,4) = batch quad.
// Each lane gathers float4 (4 batches) per index -> 16 fully-used 64B lines
// per gather instruction. Reduction over j: 4 shfl_xor steps.
// ---------------------------------------------------------------------------
__device__ __forceinline__ float4 fma4(float4 a, float s, float4 g) {
    a.x += g.x * s; a.y += g.y * s; a.z += g.z * s; a.w += g.w * s;
    return a;
}

template <int NPAIR_P, int NROWS, bool TO_WS>
__global__ __launch_bounds__(256) void patch_kernel(
    const float* __restrict__ xT,     // [TC,16]
    const int*   __restrict__ idx,    // [NROWS, NPAIR_P, 128]
    const float* __restrict__ W,      // [NROWS, NPAIR_P, 128]
    const float* __restrict__ bias,   // [NROWS, NPAIR_P]
    float*       __restrict__ dst)    // ws [B,NROWS,NPAIR_P]  or  out [B,T,460]
{
    const int wave = threadIdx.x >> 6;
    const int lane = threadIdx.x & 63;
    const int pair = blockIdx.x * 4 + wave;      // < NROWS*NPAIR_P
    const int j    = lane >> 2;                  // 0..15
    const int bq   = lane & 3;                   // 0..3

    const int4*   idx4 = (const int4*)idx + (size_t)pair * 32 + j * 2;
    const float4* w4   = (const float4*)W  + (size_t)pair * 32 + j * 2;
    const float4* xT4  = (const float4*)xT;

    const int4   ia = idx4[0];
    const int4   ib = idx4[1];
    const float4 wa = w4[0];
    const float4 wb = w4[1];

    float4 acc = make_float4(0.f, 0.f, 0.f, 0.f);
    acc = fma4(acc, wa.x, xT4[ia.x * 4 + bq]);
    acc = fma4(acc, wa.y, xT4[ia.y * 4 + bq]);
    acc = fma4(acc, wa.z, xT4[ia.z * 4 + bq]);
    acc = fma4(acc, wa.w, xT4[ia.w * 4 + bq]);
    acc = fma4(acc, wb.x, xT4[ib.x * 4 + bq]);
    acc = fma4(acc, wb.y, xT4[ib.y * 4 + bq]);
    acc = fma4(acc, wb.z, xT4[ib.z * 4 + bq]);
    acc = fma4(acc, wb.w, xT4[ib.w * 4 + bq]);

    #pragma unroll
    for (int mask = 4; mask <= 32; mask <<= 1) {
        acc.x += __shfl_xor(acc.x, mask);
        acc.y += __shfl_xor(acc.y, mask);
        acc.z += __shfl_xor(acc.z, mask);
        acc.w += __shfl_xor(acc.w, mask);
    }

    if (j == 0) {
        const float bv = bias[pair];
        const int row = pair / NPAIR_P;
        const int p   = pair - row * NPAIR_P;
        float v[4] = {acc.x, acc.y, acc.z, acc.w};
        #pragma unroll
        for (int m = 0; m < 4; ++m) {
            const int b = bq * 4 + m;
            float val = v[m] + bv;
            val = (val > 0.f) ? val : 0.3f * val;
            if (TO_WS) {
                // ws_main[b][row][p]
                dst[((size_t)b * NROWS + row) * NPAIR_P + p] = val;
            } else {
                // out[b][row][400 + p]
                dst[((size_t)b * T_LEN + row) * OUT_CH + NB_P + p] = val;
            }
        }
    }
}

// ---------------------------------------------------------------------------
// Kernel 4: upsample main result x8 along time into the output (coalesced).
// out row = 460 floats = 115 float4; main part = first 100 float4.
// ---------------------------------------------------------------------------
__global__ __launch_bounds__(256) void upsample_main(const float* __restrict__ ws_main,
                                                     float* __restrict__ out) {
    const int o4 = blockIdx.x * 256 + threadIdx.x;   // < B*T*100 = 1,638,400
    const int row = o4 / 100;
    const int col = o4 - row * 100;
    const int b = row >> 10;         // /1024
    const int t = row & 1023;
    const int s = t >> 3;            // /STRETCH
    const float4 v = ((const float4*)ws_main)[((size_t)b * S_MAIN + s) * 100 + col];
    ((float4*)out)[(size_t)row * 115 + col] = v;
}

// ---------------------------------------------------------------------------
extern "C" void kernel_launch(void* const* d_in, const int* in_sizes, int n_in,
                              void* d_out, int out_size, void* d_ws, size_t ws_size,
                              hipStream_t stream) {
    const float* x      = (const float*)d_in[0];
    const float* W_main = (const float*)d_in[1];
    const float* b_main = (const float*)d_in[2];
    const float* W_top  = (const float*)d_in[3];
    const float* b_top  = (const float*)d_in[4];
    const int*  idx_main = (const int*)d_in[5];
    const int*  idx_top  = (const int*)d_in[6];
    float* out = (float*)d_out;

    float* xT      = (float*)d_ws;                                 // 2 MB
    float* ws_main = (float*)((char*)d_ws + (size_t)TC * 16 * 4);  // 3.3 MB

    transpose_x<<<TC / 128, 256, 0, stream>>>(x, xT);

    patch_kernel<NB_P, S_MAIN, true>
        <<<(S_MAIN * NB_P) / 4, 256, 0, stream>>>(xT, idx_main, W_main, b_main, ws_main);

    patch_kernel<P_TOP, T_LEN, false>
        <<<(T_LEN * P_TOP) / 4, 256, 0, stream>>>(xT, idx_top, W_top, b_top, out);

    upsample_main<<<(B_SZ * T_LEN * 100) / 256, 256, 0, stream>>>(ws_main, out);
}

// Round 2
// 256.974 us; speedup vs baseline: 1.0120x; 1.0120x over previous
//
#include <hip/hip_runtime.h>

#define B_SZ    16
#define T_LEN   1024
#define C_CH    32
#define TC      (T_LEN * C_CH)      // 32768
#define S_MAIN  128
#define NB_P    400
#define P_TOP   60
#define KDIM    128
#define STRETCH 8
#define OUT_CH  (NB_P + P_TOP)      // 460

// ---------------------------------------------------------------------------
// Kernel 1: transpose x [B, T*C] -> xT [T*C, B] so a gather of one index
// reads 16 consecutive floats (one 64B line) covering all batches.
// ---------------------------------------------------------------------------
__global__ __launch_bounds__(256) void transpose_x(const float* __restrict__ x,
                                                   float* __restrict__ xT) {
    __shared__ float tile[16][129];   // +1 pad breaks 16-way bank conflict
    const int i0 = blockIdx.x * 128;
    const int t  = threadIdx.x;       // 0..255
    #pragma unroll
    for (int r = 0; r < 8; ++r) {
        int e  = r * 256 + t;
        int b  = e >> 7;              // /128
        int ii = e & 127;
        tile[b][ii] = x[b * TC + i0 + ii];
    }
    __syncthreads();
    #pragma unroll
    for (int r = 0; r < 8; ++r) {
        int e  = r * 256 + t;
        int ii = e >> 4;              // /16
        int b  = e & 15;
        xT[i0 * 16 + e] = tile[b][ii];   // (i0+ii)*16 + b == i0*16 + e
    }
}

// ---------------------------------------------------------------------------
// Patch compute: one wave per FOUR (row, patch) pairs (4x gather MLP).
// lane = j*4 + bq :  j in [0,16) = k-chunk of 8, bq in [0,4) = batch quad.
// Each lane gathers float4 (4 batches) per index -> 16 fully-used 64B lines
// per gather instruction. Reduction over j: 4 shfl_xor steps.
// ---------------------------------------------------------------------------
__device__ __forceinline__ float4 fma4(float4 a, float s, float4 g) {
    a.x += g.x * s; a.y += g.y * s; a.z += g.z * s; a.w += g.w * s;
    return a;
}

#define PAIRS_PER_WAVE 4

template <int NPAIR_P, int NROWS, bool TO_WS>
__global__ __launch_bounds__(256, 4) void patch_kernel(
    const float* __restrict__ xT,     // [TC,16]
    const int*   __restrict__ idx,    // [NROWS, NPAIR_P, 128]
    const float* __restrict__ W,      // [NROWS, NPAIR_P, 128]
    const float* __restrict__ bias,   // [NROWS, NPAIR_P]
    float*       __restrict__ dst)    // ws [B,NROWS,NPAIR_P]  or  out [B,T,460]
{
    const int wave  = threadIdx.x >> 6;
    const int lane  = threadIdx.x & 63;
    const int pair0 = (blockIdx.x * 4 + wave) * PAIRS_PER_WAVE;
    const int j     = lane >> 2;                 // 0..15
    const int bq    = lane & 3;                  // 0..3

    const float4* xT4 = (const float4*)xT;

    // Stage idx + W for all 4 pairs first (16 coalesced loads in flight).
    int4   ia[PAIRS_PER_WAVE], ib[PAIRS_PER_WAVE];
    float4 wa[PAIRS_PER_WAVE], wb[PAIRS_PER_WAVE];
    #pragma unroll
    for (int q = 0; q < PAIRS_PER_WAVE; ++q) {
        const int4*   i4 = (const int4*)idx + (size_t)(pair0 + q) * 32 + j * 2;
        const float4* w4 = (const float4*)W  + (size_t)(pair0 + q) * 32 + j * 2;
        ia[q] = i4[0];
        ib[q] = i4[1];
        wa[q] = w4[0];
        wb[q] = w4[1];
    }

    float4 acc[PAIRS_PER_WAVE];
    #pragma unroll
    for (int q = 0; q < PAIRS_PER_WAVE; ++q)
        acc[q] = make_float4(0.f, 0.f, 0.f, 0.f);

    #pragma unroll
    for (int q = 0; q < PAIRS_PER_WAVE; ++q) {
        acc[q] = fma4(acc[q], wa[q].x, xT4[ia[q].x * 4 + bq]);
        acc[q] = fma4(acc[q], wa[q].y, xT4[ia[q].y * 4 + bq]);
        acc[q] = fma4(acc[q], wa[q].z, xT4[ia[q].z * 4 + bq]);
        acc[q] = fma4(acc[q], wa[q].w, xT4[ia[q].w * 4 + bq]);
        acc[q] = fma4(acc[q], wb[q].x, xT4[ib[q].x * 4 + bq]);
        acc[q] = fma4(acc[q], wb[q].y, xT4[ib[q].y * 4 + bq]);
        acc[q] = fma4(acc[q], wb[q].z, xT4[ib[q].z * 4 + bq]);
        acc[q] = fma4(acc[q], wb[q].w, xT4[ib[q].w * 4 + bq]);
    }

    #pragma unroll
    for (int q = 0; q < PAIRS_PER_WAVE; ++q) {
        #pragma unroll
        for (int mask = 4; mask <= 32; mask <<= 1) {
            acc[q].x += __shfl_xor(acc[q].x, mask);
            acc[q].y += __shfl_xor(acc[q].y, mask);
            acc[q].z += __shfl_xor(acc[q].z, mask);
            acc[q].w += __shfl_xor(acc[q].w, mask);
        }
    }

    if (j == 0) {
        #pragma unroll
        for (int q = 0; q < PAIRS_PER_WAVE; ++q) {
            const int pair = pair0 + q;
            const float bv = bias[pair];
            const int row = pair / NPAIR_P;
            const int p   = pair - row * NPAIR_P;
            float v[4] = {acc[q].x, acc[q].y, acc[q].z, acc[q].w};
            #pragma unroll
            for (int m = 0; m < 4; ++m) {
                const int b = bq * 4 + m;
                float val = v[m] + bv;
                val = (val > 0.f) ? val : 0.3f * val;
                if (TO_WS) {
                    // ws_main[b][row][p]
                    dst[((size_t)b * NROWS + row) * NPAIR_P + p] = val;
                } else {
                    // out[b][row][400 + p]
                    dst[((size_t)b * T_LEN + row) * OUT_CH + NB_P + p] = val;
                }
            }
        }
    }
}

// ---------------------------------------------------------------------------
// Kernel 4: upsample main result x8 along time into the output (coalesced).
// out row = 460 floats = 115 float4; main part = first 100 float4.
// ---------------------------------------------------------------------------
__global__ __launch_bounds__(256) void upsample_main(const float* __restrict__ ws_main,
                                                     float* __restrict__ out) {
    const int o4 = blockIdx.x * 256 + threadIdx.x;   // < B*T*100 = 1,638,400
    const int row = o4 / 100;
    const int col = o4 - row * 100;
    const int b = row >> 10;         // /1024
    const int t = row & 1023;
    const int s = t >> 3;            // /STRETCH
    const float4 v = ((const float4*)ws_main)[((size_t)b * S_MAIN + s) * 100 + col];
    ((float4*)out)[(size_t)row * 115 + col] = v;
}

// ---------------------------------------------------------------------------
extern "C" void kernel_launch(void* const* d_in, const int* in_sizes, int n_in,
                              void* d_out, int out_size, void* d_ws, size_t ws_size,
                              hipStream_t stream) {
    const float* x      = (const float*)d_in[0];
    const float* W_main = (const float*)d_in[1];
    const float* b_main = (const float*)d_in[2];
    const float* W_top  = (const float*)d_in[3];
    const float* b_top  = (const float*)d_in[4];
    const int*  idx_main = (const int*)d_in[5];
    const int*  idx_top  = (const int*)d_in[6];
    float* out = (float*)d_out;

    float* xT      = (float*)d_ws;                                 // 2 MB
    float* ws_main = (float*)((char*)d_ws + (size_t)TC * 16 * 4);  // 3.3 MB

    transpose_x<<<TC / 128, 256, 0, stream>>>(x, xT);

    patch_kernel<NB_P, S_MAIN, true>
        <<<(S_MAIN * NB_P) / 16, 256, 0, stream>>>(xT, idx_main, W_main, b_main, ws_main);

    patch_kernel<P_TOP, T_LEN, false>
        <<<(T_LEN * P_TOP) / 16, 256, 0, stream>>>(xT, idx_top, W_top, b_top, out);

    upsample_main<<<(B_SZ * T_LEN * 100) / 256, 256, 0, stream>>>(ws_main, out);
}